// Round 1
// baseline (1158.620 us; speedup 1.0000x reference)
//
#include <hip/hip_runtime.h>

#define N_NODES 100000
#define N_EDGES 1600000
#define IN_DIM 128
#define HIDDEN 16
#define OUT_DIM 40
#define QMAXF 255.0f

__device__ __forceinline__ float qd_one(float x, float noise, float rmin,
                                        float rscale, float inv) {
    float q = rintf((x - rmin) * rscale + noise - 0.5f);
    q = fminf(fmaxf(q, 0.0f), QMAXF);
    return q * inv + rmin;
}

// Layer-1 fused: per-row quant-dequant of features[128] then @ W1 (128x16).
// One wave per node. Lane l holds elements 2l,2l+1.
__global__ __launch_bounds__(256) void k_qd_gemm1(
    const float* __restrict__ feat, const float* __restrict__ noise,
    const float* __restrict__ W1, float* __restrict__ y) {
    __shared__ float dqbuf[4][IN_DIM];
    const int lane = threadIdx.x & 63;
    const int wv = threadIdx.x >> 6;
    const int col = lane & 15;   // output column 0..15
    const int kg = lane >> 4;    // k-group 0..3 (32 k's each)

    // Preload W1[(kg*32+i)][col] into registers (fixed per lane).
    float w1r[32];
#pragma unroll
    for (int i = 0; i < 32; ++i) w1r[i] = W1[(kg * 32 + i) * HIDDEN + col];

    const int ngroups = N_NODES / 4;  // 25000, exact
    for (int g = blockIdx.x; g < ngroups; g += gridDim.x) {
        const int node = g * 4 + wv;
        const float2 x = ((const float2*)(feat + (size_t)node * IN_DIM))[lane];
        const float2 nz = ((const float2*)(noise + (size_t)node * IN_DIM))[lane];
        float m = fminf(x.x, x.y), M = fmaxf(x.x, x.y);
#pragma unroll
        for (int off = 1; off < 64; off <<= 1) {
            m = fminf(m, __shfl_xor(m, off));
            M = fmaxf(M, __shfl_xor(M, off));
        }
        const float rscale = QMAXF / (M - m);
        const float inv = (M - m) / QMAXF;
        float2 dq;
        dq.x = qd_one(x.x, nz.x, m, rscale, inv);
        dq.y = qd_one(x.y, nz.y, m, rscale, inv);
        ((float2*)dqbuf[wv])[lane] = dq;
        __syncthreads();
        float acc = 0.0f;
        const float* dqk = dqbuf[wv] + kg * 32;
#pragma unroll
        for (int i = 0; i < 32; ++i) acc += dqk[i] * w1r[i];
        acc += __shfl_xor(acc, 16);
        acc += __shfl_xor(acc, 32);
        if (lane < 16) y[(size_t)node * HIDDEN + lane] = acc;
        __syncthreads();
    }
}

// COO SpMM at d=16: 4 threads per edge, float4 gather + 4 scalar f32 atomics.
__global__ __launch_bounds__(256) void k_spmm(
    const int* __restrict__ row, const int* __restrict__ col,
    const float* __restrict__ vals, const float* __restrict__ y,
    float* __restrict__ z) {
    const int tid = blockIdx.x * 256 + threadIdx.x;  // e*4 + c, exact grid
    const int e = tid >> 2;
    const int c = tid & 3;
    const int r = row[e];
    const int cl = col[e];
    const float v = vals[e];
    const float4 s = ((const float4*)y)[cl * 4 + c];
    float* zp = z + (size_t)r * HIDDEN + c * 4;
    atomicAdd(zp + 0, v * s.x);
    atomicAdd(zp + 1, v * s.y);
    atomicAdd(zp + 2, v * s.z);
    atomicAdd(zp + 3, v * s.w);
}

// relu + quant-dequant of a 16-wide row, then @ W2 (16x16). Thread per node.
__global__ __launch_bounds__(256) void k_qd_gemm16(
    const float* __restrict__ zin, const float* __restrict__ noise,
    const float* __restrict__ W2, float* __restrict__ y) {
    __shared__ float w[HIDDEN * HIDDEN];
    w[threadIdx.x] = W2[threadIdx.x];
    __syncthreads();
    const int t = blockIdx.x * 256 + threadIdx.x;
    if (t >= N_NODES) return;
    float x[16], nz[16];
    {
        const float4* zr = (const float4*)(zin + (size_t)t * HIDDEN);
        const float4* nr = (const float4*)(noise + (size_t)t * HIDDEN);
#pragma unroll
        for (int i = 0; i < 4; ++i) {
            ((float4*)x)[i] = zr[i];
            ((float4*)nz)[i] = nr[i];
        }
    }
#pragma unroll
    for (int i = 0; i < 16; ++i) x[i] = fmaxf(x[i], 0.0f);  // relu
    float m = x[0], M = x[0];
#pragma unroll
    for (int i = 1; i < 16; ++i) { m = fminf(m, x[i]); M = fmaxf(M, x[i]); }
    const float rscale = QMAXF / (M - m);
    const float inv = (M - m) / QMAXF;
    float acc[16];
#pragma unroll
    for (int j = 0; j < 16; ++j) acc[j] = 0.0f;
#pragma unroll
    for (int k = 0; k < 16; ++k) {
        const float d = qd_one(x[k], nz[k], m, rscale, inv);
        const float4* wr = (const float4*)(w + k * 16);
#pragma unroll
        for (int j4 = 0; j4 < 4; ++j4) {
            float4 ww = wr[j4];
            acc[4 * j4 + 0] += d * ww.x;
            acc[4 * j4 + 1] += d * ww.y;
            acc[4 * j4 + 2] += d * ww.z;
            acc[4 * j4 + 3] += d * ww.w;
        }
    }
    float4* yr = (float4*)(y + (size_t)t * HIDDEN);
#pragma unroll
    for (int i = 0; i < 4; ++i) yr[i] = ((float4*)acc)[i];
}

// relu + quant-dequant only (layer 3 pre-spmm). Thread per node.
__global__ __launch_bounds__(256) void k_qd16(
    const float* __restrict__ zin, const float* __restrict__ noise,
    float* __restrict__ y) {
    const int t = blockIdx.x * 256 + threadIdx.x;
    if (t >= N_NODES) return;
    float x[16], nz[16];
    {
        const float4* zr = (const float4*)(zin + (size_t)t * HIDDEN);
        const float4* nr = (const float4*)(noise + (size_t)t * HIDDEN);
#pragma unroll
        for (int i = 0; i < 4; ++i) {
            ((float4*)x)[i] = zr[i];
            ((float4*)nz)[i] = nr[i];
        }
    }
#pragma unroll
    for (int i = 0; i < 16; ++i) x[i] = fmaxf(x[i], 0.0f);
    float m = x[0], M = x[0];
#pragma unroll
    for (int i = 1; i < 16; ++i) { m = fminf(m, x[i]); M = fmaxf(M, x[i]); }
    const float rscale = QMAXF / (M - m);
    const float inv = (M - m) / QMAXF;
    float dq[16];
#pragma unroll
    for (int i = 0; i < 16; ++i) dq[i] = qd_one(x[i], nz[i], m, rscale, inv);
    float4* yr = (float4*)(y + (size_t)t * HIDDEN);
#pragma unroll
    for (int i = 0; i < 4; ++i) yr[i] = ((float4*)dq)[i];
}

// out = z3 @ W3 (16 -> 40). Thread per node.
__global__ __launch_bounds__(256) void k_gemm_out(
    const float* __restrict__ z, const float* __restrict__ W3,
    float* __restrict__ out) {
    __shared__ float w[HIDDEN * OUT_DIM];  // 640 floats
    for (int i = threadIdx.x; i < HIDDEN * OUT_DIM; i += 256) w[i] = W3[i];
    __syncthreads();
    const int t = blockIdx.x * 256 + threadIdx.x;
    if (t >= N_NODES) return;
    float x[16];
    {
        const float4* zr = (const float4*)(z + (size_t)t * HIDDEN);
#pragma unroll
        for (int i = 0; i < 4; ++i) ((float4*)x)[i] = zr[i];
    }
    float acc[OUT_DIM];
#pragma unroll
    for (int j = 0; j < OUT_DIM; ++j) acc[j] = 0.0f;
#pragma unroll
    for (int k = 0; k < 16; ++k) {
        const float d = x[k];
        const float4* wr = (const float4*)(w + k * OUT_DIM);
#pragma unroll
        for (int j4 = 0; j4 < OUT_DIM / 4; ++j4) {
            float4 ww = wr[j4];
            acc[4 * j4 + 0] += d * ww.x;
            acc[4 * j4 + 1] += d * ww.y;
            acc[4 * j4 + 2] += d * ww.z;
            acc[4 * j4 + 3] += d * ww.w;
        }
    }
    float4* orow = (float4*)(out + (size_t)t * OUT_DIM);
#pragma unroll
    for (int i = 0; i < OUT_DIM / 4; ++i) orow[i] = ((float4*)acc)[i];
}

extern "C" void kernel_launch(void* const* d_in, const int* in_sizes, int n_in,
                              void* d_out, int out_size, void* d_ws,
                              size_t ws_size, hipStream_t stream) {
    const float* feat = (const float*)d_in[0];
    const int* row = (const int*)d_in[1];
    const int* col = (const int*)d_in[2];
    const float* vals = (const float*)d_in[3];
    const float* W1 = (const float*)d_in[4];
    const float* W2 = (const float*)d_in[5];
    const float* W3 = (const float*)d_in[6];
    const float* n1 = (const float*)d_in[7];
    const float* n2 = (const float*)d_in[8];
    const float* n3 = (const float*)d_in[9];
    float* out = (float*)d_out;

    float* A = (float*)d_ws;               // 100000*16 floats
    float* B = A + (size_t)N_NODES * HIDDEN;  // 100000*16 floats
    const size_t zbytes = (size_t)N_NODES * HIDDEN * sizeof(float);

    const int nodeBlocks = (N_NODES + 255) / 256;
    const int spmmBlocks = (N_EDGES * 4) / 256;  // exact: 25000

    // Layer 1: y1 = qd(features) @ W1 ; z1 = A_graph @ y1
    k_qd_gemm1<<<2500, 256, 0, stream>>>(feat, n1, W1, A);
    hipMemsetAsync(B, 0, zbytes, stream);
    k_spmm<<<spmmBlocks, 256, 0, stream>>>(row, col, vals, A, B);

    // Layer 2: y2 = qd(relu(z1)) @ W2 ; z2 = A_graph @ y2
    k_qd_gemm16<<<nodeBlocks, 256, 0, stream>>>(B, n2, W2, A);
    hipMemsetAsync(B, 0, zbytes, stream);
    k_spmm<<<spmmBlocks, 256, 0, stream>>>(row, col, vals, A, B);

    // Layer 3: t3 = qd(relu(z2)) ; z3 = A_graph @ t3 ; out = z3 @ W3
    k_qd16<<<nodeBlocks, 256, 0, stream>>>(B, n3, A);
    hipMemsetAsync(B, 0, zbytes, stream);
    k_spmm<<<spmmBlocks, 256, 0, stream>>>(row, col, vals, A, B);
    k_gemm_out<<<nodeBlocks, 256, 0, stream>>>(B, W3, out);
}

// Round 2
// 471.706 us; speedup vs baseline: 2.4562x; 2.4562x over previous
//
#include <hip/hip_runtime.h>

#define N_NODES 100000
#define N_EDGES 1600000
#define IN_DIM 128
#define HIDDEN 16
#define OUT_DIM 40
#define QMAXF 255.0f

#define SCAN_CHUNK 1024  // elements per scan block (256 thr x 4)
#define SCAN_BLOCKS ((N_NODES + SCAN_CHUNK - 1) / SCAN_CHUNK)  // 98

__device__ __forceinline__ float qd_one(float x, float noise, float rmin,
                                        float rscale, float inv) {
    float q = rintf((x - rmin) * rscale + noise - 0.5f);
    q = fminf(fmaxf(q, 0.0f), QMAXF);
    return q * inv + rmin;
}

// ---------------- CSR construction (graph is reused by all 3 layers) --------

__global__ __launch_bounds__(256) void k_hist(const int* __restrict__ row,
                                              int* __restrict__ ptr) {
    const int e = blockIdx.x * 256 + threadIdx.x;
    if (e < N_EDGES) atomicAdd(&ptr[row[e]], 1);
}

// Per-block exclusive scan over 1024-element chunks; block totals -> aux.
__global__ __launch_bounds__(256) void k_scan1(int* __restrict__ ptr,
                                               int* __restrict__ aux) {
    __shared__ int s[256];
    const int t = threadIdx.x;
    const int idx = blockIdx.x * SCAN_CHUNK + t * 4;
    int v[4];
#pragma unroll
    for (int i = 0; i < 4; ++i) v[i] = (idx + i < N_NODES) ? ptr[idx + i] : 0;
    s[t] = v[0] + v[1] + v[2] + v[3];
    __syncthreads();
    for (int off = 1; off < 256; off <<= 1) {
        int x = (t >= off) ? s[t - off] : 0;
        __syncthreads();
        s[t] += x;
        __syncthreads();
    }
    if (t == 255) aux[blockIdx.x] = s[255];
    int run = (t == 0) ? 0 : s[t - 1];
#pragma unroll
    for (int i = 0; i < 4; ++i) {
        int tmp = v[i];
        if (idx + i < N_NODES) ptr[idx + i] = run;
        run += tmp;
    }
}

__global__ void k_scan2(int* __restrict__ aux) {
    if (threadIdx.x == 0 && blockIdx.x == 0) {
        int run = 0;
        for (int i = 0; i < SCAN_BLOCKS; ++i) {
            int t = aux[i];
            aux[i] = run;
            run += t;
        }
    }
}

__global__ __launch_bounds__(256) void k_scan3(int* __restrict__ ptr,
                                               const int* __restrict__ aux) {
    const int idx = blockIdx.x * SCAN_CHUNK + threadIdx.x * 4;
    const int add = aux[blockIdx.x];
#pragma unroll
    for (int i = 0; i < 4; ++i)
        if (idx + i < N_NODES) ptr[idx + i] += add;
}

// Bucket-scatter edges into CSR order. Afterwards ptr[i] == end of row i.
__global__ __launch_bounds__(256) void k_scatter(
    const int* __restrict__ row, const int* __restrict__ col,
    const float* __restrict__ vals, int* __restrict__ ptr,
    int* __restrict__ cs, float* __restrict__ vs) {
    const int e = blockIdx.x * 256 + threadIdx.x;
    if (e >= N_EDGES) return;
    const int pos = atomicAdd(&ptr[row[e]], 1);
    cs[pos] = col[e];
    vs[pos] = vals[e];
}

// Gather SpMM: 4 threads per node, float4 each. No atomics, writes z once.
// ptrEnd[i] = end of row i; start = ptrEnd[i-1] (0 for i==0).
__global__ __launch_bounds__(256) void k_spmm_csr(
    const int* __restrict__ ptrEnd, const int* __restrict__ cs,
    const float* __restrict__ vs, const float* __restrict__ y,
    float* __restrict__ z) {
    const int tid = blockIdx.x * 256 + threadIdx.x;
    const int i = tid >> 2;
    const int c = tid & 3;
    if (i >= N_NODES) return;
    const int start = (i == 0) ? 0 : ptrEnd[i - 1];
    const int end = ptrEnd[i];
    float4 acc = {0.0f, 0.0f, 0.0f, 0.0f};
    for (int j = start; j < end; ++j) {
        const int cl = cs[j];
        const float v = vs[j];
        const float4 s = ((const float4*)y)[cl * 4 + c];
        acc.x += v * s.x;
        acc.y += v * s.y;
        acc.z += v * s.z;
        acc.w += v * s.w;
    }
    ((float4*)z)[(size_t)i * 4 + c] = acc;
}

// ---------------- dense / quant kernels (unchanged from R1) ----------------

__global__ __launch_bounds__(256) void k_qd_gemm1(
    const float* __restrict__ feat, const float* __restrict__ noise,
    const float* __restrict__ W1, float* __restrict__ y) {
    __shared__ float dqbuf[4][IN_DIM];
    const int lane = threadIdx.x & 63;
    const int wv = threadIdx.x >> 6;
    const int col = lane & 15;
    const int kg = lane >> 4;

    float w1r[32];
#pragma unroll
    for (int i = 0; i < 32; ++i) w1r[i] = W1[(kg * 32 + i) * HIDDEN + col];

    const int ngroups = N_NODES / 4;  // 25000
    for (int g = blockIdx.x; g < ngroups; g += gridDim.x) {
        const int node = g * 4 + wv;
        const float2 x = ((const float2*)(feat + (size_t)node * IN_DIM))[lane];
        const float2 nz = ((const float2*)(noise + (size_t)node * IN_DIM))[lane];
        float m = fminf(x.x, x.y), M = fmaxf(x.x, x.y);
#pragma unroll
        for (int off = 1; off < 64; off <<= 1) {
            m = fminf(m, __shfl_xor(m, off));
            M = fmaxf(M, __shfl_xor(M, off));
        }
        const float rscale = QMAXF / (M - m);
        const float inv = (M - m) / QMAXF;
        float2 dq;
        dq.x = qd_one(x.x, nz.x, m, rscale, inv);
        dq.y = qd_one(x.y, nz.y, m, rscale, inv);
        ((float2*)dqbuf[wv])[lane] = dq;
        __syncthreads();
        float acc = 0.0f;
        const float* dqk = dqbuf[wv] + kg * 32;
#pragma unroll
        for (int i = 0; i < 32; ++i) acc += dqk[i] * w1r[i];
        acc += __shfl_xor(acc, 16);
        acc += __shfl_xor(acc, 32);
        if (lane < 16) y[(size_t)node * HIDDEN + lane] = acc;
        __syncthreads();
    }
}

__global__ __launch_bounds__(256) void k_qd_gemm16(
    const float* __restrict__ zin, const float* __restrict__ noise,
    const float* __restrict__ W2, float* __restrict__ y) {
    __shared__ float w[HIDDEN * HIDDEN];
    w[threadIdx.x] = W2[threadIdx.x];
    __syncthreads();
    const int t = blockIdx.x * 256 + threadIdx.x;
    if (t >= N_NODES) return;
    float x[16], nz[16];
    {
        const float4* zr = (const float4*)(zin + (size_t)t * HIDDEN);
        const float4* nr = (const float4*)(noise + (size_t)t * HIDDEN);
#pragma unroll
        for (int i = 0; i < 4; ++i) {
            ((float4*)x)[i] = zr[i];
            ((float4*)nz)[i] = nr[i];
        }
    }
#pragma unroll
    for (int i = 0; i < 16; ++i) x[i] = fmaxf(x[i], 0.0f);
    float m = x[0], M = x[0];
#pragma unroll
    for (int i = 1; i < 16; ++i) { m = fminf(m, x[i]); M = fmaxf(M, x[i]); }
    const float rscale = QMAXF / (M - m);
    const float inv = (M - m) / QMAXF;
    float acc[16];
#pragma unroll
    for (int j = 0; j < 16; ++j) acc[j] = 0.0f;
#pragma unroll
    for (int k = 0; k < 16; ++k) {
        const float d = qd_one(x[k], nz[k], m, rscale, inv);
        const float4* wr = (const float4*)(w + k * 16);
#pragma unroll
        for (int j4 = 0; j4 < 4; ++j4) {
            float4 ww = wr[j4];
            acc[4 * j4 + 0] += d * ww.x;
            acc[4 * j4 + 1] += d * ww.y;
            acc[4 * j4 + 2] += d * ww.z;
            acc[4 * j4 + 3] += d * ww.w;
        }
    }
    float4* yr = (float4*)(y + (size_t)t * HIDDEN);
#pragma unroll
    for (int i = 0; i < 4; ++i) yr[i] = ((float4*)acc)[i];
}

__global__ __launch_bounds__(256) void k_qd16(
    const float* __restrict__ zin, const float* __restrict__ noise,
    float* __restrict__ y) {
    const int t = blockIdx.x * 256 + threadIdx.x;
    if (t >= N_NODES) return;
    float x[16], nz[16];
    {
        const float4* zr = (const float4*)(zin + (size_t)t * HIDDEN);
        const float4* nr = (const float4*)(noise + (size_t)t * HIDDEN);
#pragma unroll
        for (int i = 0; i < 4; ++i) {
            ((float4*)x)[i] = zr[i];
            ((float4*)nz)[i] = nr[i];
        }
    }
#pragma unroll
    for (int i = 0; i < 16; ++i) x[i] = fmaxf(x[i], 0.0f);
    float m = x[0], M = x[0];
#pragma unroll
    for (int i = 1; i < 16; ++i) { m = fminf(m, x[i]); M = fmaxf(M, x[i]); }
    const float rscale = QMAXF / (M - m);
    const float inv = (M - m) / QMAXF;
    float dq[16];
#pragma unroll
    for (int i = 0; i < 16; ++i) dq[i] = qd_one(x[i], nz[i], m, rscale, inv);
    float4* yr = (float4*)(y + (size_t)t * HIDDEN);
#pragma unroll
    for (int i = 0; i < 4; ++i) yr[i] = ((float4*)dq)[i];
}

__global__ __launch_bounds__(256) void k_gemm_out(
    const float* __restrict__ z, const float* __restrict__ W3,
    float* __restrict__ out) {
    __shared__ float w[HIDDEN * OUT_DIM];
    for (int i = threadIdx.x; i < HIDDEN * OUT_DIM; i += 256) w[i] = W3[i];
    __syncthreads();
    const int t = blockIdx.x * 256 + threadIdx.x;
    if (t >= N_NODES) return;
    float x[16];
    {
        const float4* zr = (const float4*)(z + (size_t)t * HIDDEN);
#pragma unroll
        for (int i = 0; i < 4; ++i) ((float4*)x)[i] = zr[i];
    }
    float acc[OUT_DIM];
#pragma unroll
    for (int j = 0; j < OUT_DIM; ++j) acc[j] = 0.0f;
#pragma unroll
    for (int k = 0; k < 16; ++k) {
        const float d = x[k];
        const float4* wr = (const float4*)(w + k * OUT_DIM);
#pragma unroll
        for (int j4 = 0; j4 < OUT_DIM / 4; ++j4) {
            float4 ww = wr[j4];
            acc[4 * j4 + 0] += d * ww.x;
            acc[4 * j4 + 1] += d * ww.y;
            acc[4 * j4 + 2] += d * ww.z;
            acc[4 * j4 + 3] += d * ww.w;
        }
    }
    float4* orow = (float4*)(out + (size_t)t * OUT_DIM);
#pragma unroll
    for (int i = 0; i < OUT_DIM / 4; ++i) orow[i] = ((float4*)acc)[i];
}

extern "C" void kernel_launch(void* const* d_in, const int* in_sizes, int n_in,
                              void* d_out, int out_size, void* d_ws,
                              size_t ws_size, hipStream_t stream) {
    const float* feat = (const float*)d_in[0];
    const int* row = (const int*)d_in[1];
    const int* col = (const int*)d_in[2];
    const float* vals = (const float*)d_in[3];
    const float* W1 = (const float*)d_in[4];
    const float* W2 = (const float*)d_in[5];
    const float* W3 = (const float*)d_in[6];
    const float* n1 = (const float*)d_in[7];
    const float* n2 = (const float*)d_in[8];
    const float* n3 = (const float*)d_in[9];
    float* out = (float*)d_out;

    // Workspace layout (all 4-byte elements):
    float* A = (float*)d_ws;                         // N*16 floats
    float* B = A + (size_t)N_NODES * HIDDEN;         // N*16 floats
    int* ptr = (int*)(B + (size_t)N_NODES * HIDDEN); // N ints
    int* aux = ptr + N_NODES;                        // 128 ints
    int* cs = aux + 128;                             // E ints
    float* vs = (float*)(cs + N_EDGES);              // E floats

    const int nodeBlocks = (N_NODES + 255) / 256;
    const int edgeBlocks = (N_EDGES + 255) / 256;          // 6250
    const int spmmBlocks = (N_NODES * 4 + 255) / 256;      // 1563

    // --- CSR build (once; reused by all 3 SpMMs) ---
    hipMemsetAsync(ptr, 0, (size_t)N_NODES * sizeof(int), stream);
    k_hist<<<edgeBlocks, 256, 0, stream>>>(row, ptr);
    k_scan1<<<SCAN_BLOCKS, 256, 0, stream>>>(ptr, aux);
    k_scan2<<<1, 64, 0, stream>>>(aux);
    k_scan3<<<SCAN_BLOCKS, 256, 0, stream>>>(ptr, aux);
    k_scatter<<<edgeBlocks, 256, 0, stream>>>(row, col, vals, ptr, cs, vs);
    // ptr[i] now holds END of row i.

    // Layer 1: y1 = qd(features) @ W1 ; z1 = A_graph @ y1
    k_qd_gemm1<<<2500, 256, 0, stream>>>(feat, n1, W1, A);
    k_spmm_csr<<<spmmBlocks, 256, 0, stream>>>(ptr, cs, vs, A, B);

    // Layer 2: y2 = qd(relu(z1)) @ W2 ; z2 = A_graph @ y2
    k_qd_gemm16<<<nodeBlocks, 256, 0, stream>>>(B, n2, W2, A);
    k_spmm_csr<<<spmmBlocks, 256, 0, stream>>>(ptr, cs, vs, A, B);

    // Layer 3: t3 = qd(relu(z2)) ; z3 = A_graph @ t3 ; out = z3 @ W3
    k_qd16<<<nodeBlocks, 256, 0, stream>>>(B, n3, A);
    k_spmm_csr<<<spmmBlocks, 256, 0, stream>>>(ptr, cs, vs, A, B);
    k_gemm_out<<<nodeBlocks, 256, 0, stream>>>(B, W3, out);
}

// Round 3
// 445.861 us; speedup vs baseline: 2.5986x; 1.0580x over previous
//
#include <hip/hip_runtime.h>

#define N_NODES 100000
#define N_EDGES 1600000
#define IN_DIM 128
#define HIDDEN 16
#define OUT_DIM 40
#define QMAXF 255.0f

#define NCOLOR 8
#define ROWS_PER_COLOR (N_NODES / NCOLOR)  // 12500
#define NCHUNK (N_EDGES / 256)             // 6250

#define SCAN_CHUNK 1024
#define SCAN_BLOCKS ((N_NODES + SCAN_CHUNK - 1) / SCAN_CHUNK)  // 98

__device__ __forceinline__ float qd_one(float x, float noise, float rmin,
                                        float rscale, float inv) {
    float q = rintf((x - rmin) * rscale + noise - 0.5f);
    q = fminf(fmaxf(q, 0.0f), QMAXF);
    return q * inv + rmin;
}

// ---------------- CSR construction -----------------------------------------

__global__ __launch_bounds__(256) void k_hist(const int* __restrict__ row,
                                              int* __restrict__ ptr) {
    const int e = blockIdx.x * 256 + threadIdx.x;
    if (e < N_EDGES) atomicAdd(&ptr[row[e]], 1);
}

__global__ __launch_bounds__(256) void k_scan1(int* __restrict__ ptr,
                                               int* __restrict__ aux) {
    __shared__ int s[256];
    const int t = threadIdx.x;
    const int idx = blockIdx.x * SCAN_CHUNK + t * 4;
    int v[4];
#pragma unroll
    for (int i = 0; i < 4; ++i) v[i] = (idx + i < N_NODES) ? ptr[idx + i] : 0;
    s[t] = v[0] + v[1] + v[2] + v[3];
    __syncthreads();
    for (int off = 1; off < 256; off <<= 1) {
        int x = (t >= off) ? s[t - off] : 0;
        __syncthreads();
        s[t] += x;
        __syncthreads();
    }
    if (t == 255) aux[blockIdx.x] = s[255];
    int run = (t == 0) ? 0 : s[t - 1];
#pragma unroll
    for (int i = 0; i < 4; ++i) {
        int tmp = v[i];
        if (idx + i < N_NODES) ptr[idx + i] = run;
        run += tmp;
    }
}

__global__ void k_scan2(int* __restrict__ aux) {
    if (threadIdx.x == 0 && blockIdx.x == 0) {
        int run = 0;
        for (int i = 0; i < SCAN_BLOCKS; ++i) {
            int t = aux[i];
            aux[i] = run;
            run += t;
        }
    }
}

__global__ __launch_bounds__(256) void k_scan3(int* __restrict__ ptr,
                                               const int* __restrict__ aux) {
    const int idx = blockIdx.x * SCAN_CHUNK + threadIdx.x * 4;
    const int add = aux[blockIdx.x];
#pragma unroll
    for (int i = 0; i < 4; ++i)
        if (idx + i < N_NODES) ptr[idx + i] += add;
}

// Color-partitioned packed scatter. color = blockIdx & 7 (XCD round-robin
// heuristic): each color's contiguous ~1.6 MB CSR slice stays resident in
// one XCD's L2 so lines fill fully before writeback. Every chunk is read by
// 8 blocks (8x coalesced fetch) — cheap vs partial-line writeback churn.
__global__ __launch_bounds__(256) void k_scatter(
    const int* __restrict__ row, const int* __restrict__ col,
    const float* __restrict__ vals, int* __restrict__ ptr,
    int2* __restrict__ es) {
    const int color = blockIdx.x & (NCOLOR - 1);
    const int chunk = blockIdx.x >> 3;
    const int e = chunk * 256 + threadIdx.x;
    const int r = row[e];
    const unsigned rel = (unsigned)(r - color * ROWS_PER_COLOR);
    if (rel < ROWS_PER_COLOR) {
        const int pos = atomicAdd(&ptr[r], 1);
        es[pos] = make_int2(col[e], __float_as_int(vals[e]));
    }
}

// Wave-per-node gather SpMM. lane = slot*4 + c: 16 edge slots x 4 col-groups.
// 16 gathers in flight per wave-iteration; shfl_xor tree-reduce over slots.
__global__ __launch_bounds__(256) void k_spmm_wave(
    const int* __restrict__ ptrEnd, const int2* __restrict__ es,
    const float* __restrict__ y, float* __restrict__ z) {
    const int wv = threadIdx.x >> 6;
    const int lane = threadIdx.x & 63;
    const int i = blockIdx.x * 4 + wv;
    if (i >= N_NODES) return;
    const int slot = lane >> 2;
    const int c = lane & 3;
    const int start = (i == 0) ? 0 : ptrEnd[i - 1];
    const int end = ptrEnd[i];
    float4 acc = {0.0f, 0.0f, 0.0f, 0.0f};
    for (int j = start + slot; j < end; j += 16) {
        const int2 e = es[j];
        const float v = __int_as_float(e.y);
        const float4 s = ((const float4*)y)[e.x * 4 + c];
        acc.x += v * s.x;
        acc.y += v * s.y;
        acc.z += v * s.z;
        acc.w += v * s.w;
    }
#pragma unroll
    for (int off = 4; off < 64; off <<= 1) {
        acc.x += __shfl_xor(acc.x, off);
        acc.y += __shfl_xor(acc.y, off);
        acc.z += __shfl_xor(acc.z, off);
        acc.w += __shfl_xor(acc.w, off);
    }
    if (lane < 4) ((float4*)z)[(size_t)i * 4 + lane] = acc;
}

// ---------------- dense / quant kernels ------------------------------------

__global__ __launch_bounds__(256) void k_qd_gemm1(
    const float* __restrict__ feat, const float* __restrict__ noise,
    const float* __restrict__ W1, float* __restrict__ y) {
    __shared__ float dqbuf[4][IN_DIM];
    const int lane = threadIdx.x & 63;
    const int wv = threadIdx.x >> 6;
    const int col = lane & 15;
    const int kg = lane >> 4;

    float w1r[32];
#pragma unroll
    for (int i = 0; i < 32; ++i) w1r[i] = W1[(kg * 32 + i) * HIDDEN + col];

    const int ngroups = N_NODES / 4;  // 25000
    for (int g = blockIdx.x; g < ngroups; g += gridDim.x) {
        const int node = g * 4 + wv;
        const float2 x = ((const float2*)(feat + (size_t)node * IN_DIM))[lane];
        const float2 nz = ((const float2*)(noise + (size_t)node * IN_DIM))[lane];
        float m = fminf(x.x, x.y), M = fmaxf(x.x, x.y);
#pragma unroll
        for (int off = 1; off < 64; off <<= 1) {
            m = fminf(m, __shfl_xor(m, off));
            M = fmaxf(M, __shfl_xor(M, off));
        }
        const float rscale = QMAXF / (M - m);
        const float inv = (M - m) / QMAXF;
        float2 dq;
        dq.x = qd_one(x.x, nz.x, m, rscale, inv);
        dq.y = qd_one(x.y, nz.y, m, rscale, inv);
        ((float2*)dqbuf[wv])[lane] = dq;
        __syncthreads();
        float acc = 0.0f;
        const float* dqk = dqbuf[wv] + kg * 32;
#pragma unroll
        for (int i = 0; i < 32; ++i) acc += dqk[i] * w1r[i];
        acc += __shfl_xor(acc, 16);
        acc += __shfl_xor(acc, 32);
        if (lane < 16) y[(size_t)node * HIDDEN + lane] = acc;
        __syncthreads();
    }
}

__global__ __launch_bounds__(256) void k_qd_gemm16(
    const float* __restrict__ zin, const float* __restrict__ noise,
    const float* __restrict__ W2, float* __restrict__ y) {
    __shared__ float w[HIDDEN * HIDDEN];
    w[threadIdx.x] = W2[threadIdx.x];
    __syncthreads();
    const int t = blockIdx.x * 256 + threadIdx.x;
    if (t >= N_NODES) return;
    float x[16], nz[16];
    {
        const float4* zr = (const float4*)(zin + (size_t)t * HIDDEN);
        const float4* nr = (const float4*)(noise + (size_t)t * HIDDEN);
#pragma unroll
        for (int i = 0; i < 4; ++i) {
            ((float4*)x)[i] = zr[i];
            ((float4*)nz)[i] = nr[i];
        }
    }
#pragma unroll
    for (int i = 0; i < 16; ++i) x[i] = fmaxf(x[i], 0.0f);
    float m = x[0], M = x[0];
#pragma unroll
    for (int i = 1; i < 16; ++i) { m = fminf(m, x[i]); M = fmaxf(M, x[i]); }
    const float rscale = QMAXF / (M - m);
    const float inv = (M - m) / QMAXF;
    float acc[16];
#pragma unroll
    for (int j = 0; j < 16; ++j) acc[j] = 0.0f;
#pragma unroll
    for (int k = 0; k < 16; ++k) {
        const float d = qd_one(x[k], nz[k], m, rscale, inv);
        const float4* wr = (const float4*)(w + k * 16);
#pragma unroll
        for (int j4 = 0; j4 < 4; ++j4) {
            float4 ww = wr[j4];
            acc[4 * j4 + 0] += d * ww.x;
            acc[4 * j4 + 1] += d * ww.y;
            acc[4 * j4 + 2] += d * ww.z;
            acc[4 * j4 + 3] += d * ww.w;
        }
    }
    float4* yr = (float4*)(y + (size_t)t * HIDDEN);
#pragma unroll
    for (int i = 0; i < 4; ++i) yr[i] = ((float4*)acc)[i];
}

__global__ __launch_bounds__(256) void k_qd16(
    const float* __restrict__ zin, const float* __restrict__ noise,
    float* __restrict__ y) {
    const int t = blockIdx.x * 256 + threadIdx.x;
    if (t >= N_NODES) return;
    float x[16], nz[16];
    {
        const float4* zr = (const float4*)(zin + (size_t)t * HIDDEN);
        const float4* nr = (const float4*)(noise + (size_t)t * HIDDEN);
#pragma unroll
        for (int i = 0; i < 4; ++i) {
            ((float4*)x)[i] = zr[i];
            ((float4*)nz)[i] = nr[i];
        }
    }
#pragma unroll
    for (int i = 0; i < 16; ++i) x[i] = fmaxf(x[i], 0.0f);
    float m = x[0], M = x[0];
#pragma unroll
    for (int i = 1; i < 16; ++i) { m = fminf(m, x[i]); M = fmaxf(M, x[i]); }
    const float rscale = QMAXF / (M - m);
    const float inv = (M - m) / QMAXF;
    float dq[16];
#pragma unroll
    for (int i = 0; i < 16; ++i) dq[i] = qd_one(x[i], nz[i], m, rscale, inv);
    float4* yr = (float4*)(y + (size_t)t * HIDDEN);
#pragma unroll
    for (int i = 0; i < 4; ++i) yr[i] = ((float4*)dq)[i];
}

__global__ __launch_bounds__(256) void k_gemm_out(
    const float* __restrict__ z, const float* __restrict__ W3,
    float* __restrict__ out) {
    __shared__ float w[HIDDEN * OUT_DIM];
    for (int i = threadIdx.x; i < HIDDEN * OUT_DIM; i += 256) w[i] = W3[i];
    __syncthreads();
    const int t = blockIdx.x * 256 + threadIdx.x;
    if (t >= N_NODES) return;
    float x[16];
    {
        const float4* zr = (const float4*)(z + (size_t)t * HIDDEN);
#pragma unroll
        for (int i = 0; i < 4; ++i) ((float4*)x)[i] = zr[i];
    }
    float acc[OUT_DIM];
#pragma unroll
    for (int j = 0; j < OUT_DIM; ++j) acc[j] = 0.0f;
#pragma unroll
    for (int k = 0; k < 16; ++k) {
        const float d = x[k];
        const float4* wr = (const float4*)(w + k * OUT_DIM);
#pragma unroll
        for (int j4 = 0; j4 < OUT_DIM / 4; ++j4) {
            float4 ww = wr[j4];
            acc[4 * j4 + 0] += d * ww.x;
            acc[4 * j4 + 1] += d * ww.y;
            acc[4 * j4 + 2] += d * ww.z;
            acc[4 * j4 + 3] += d * ww.w;
        }
    }
    float4* orow = (float4*)(out + (size_t)t * OUT_DIM);
#pragma unroll
    for (int i = 0; i < OUT_DIM / 4; ++i) orow[i] = ((float4*)acc)[i];
}

extern "C" void kernel_launch(void* const* d_in, const int* in_sizes, int n_in,
                              void* d_out, int out_size, void* d_ws,
                              size_t ws_size, hipStream_t stream) {
    const float* feat = (const float*)d_in[0];
    const int* row = (const int*)d_in[1];
    const int* col = (const int*)d_in[2];
    const float* vals = (const float*)d_in[3];
    const float* W1 = (const float*)d_in[4];
    const float* W2 = (const float*)d_in[5];
    const float* W3 = (const float*)d_in[6];
    const float* n1 = (const float*)d_in[7];
    const float* n2 = (const float*)d_in[8];
    const float* n3 = (const float*)d_in[9];
    float* out = (float*)d_out;

    float* A = (float*)d_ws;                          // N*16 floats
    float* B = A + (size_t)N_NODES * HIDDEN;          // N*16 floats
    int* ptr = (int*)(B + (size_t)N_NODES * HIDDEN);  // N ints
    int* aux = ptr + N_NODES;                         // 128 ints
    int2* es = (int2*)(aux + 128);                    // E int2 (packed col,val)

    const int nodeBlocks = (N_NODES + 255) / 256;
    const int edgeBlocks = (N_EDGES + 255) / 256;  // 6250
    const int spmmBlocks = N_NODES / 4;            // 25000, exact

    // --- CSR build (once; reused by all 3 SpMMs) ---
    hipMemsetAsync(ptr, 0, (size_t)N_NODES * sizeof(int), stream);
    k_hist<<<edgeBlocks, 256, 0, stream>>>(row, ptr);
    k_scan1<<<SCAN_BLOCKS, 256, 0, stream>>>(ptr, aux);
    k_scan2<<<1, 64, 0, stream>>>(aux);
    k_scan3<<<SCAN_BLOCKS, 256, 0, stream>>>(ptr, aux);
    k_scatter<<<NCOLOR * NCHUNK, 256, 0, stream>>>(row, col, vals, ptr, es);
    // ptr[i] now holds END of row i.

    // Layer 1
    k_qd_gemm1<<<2500, 256, 0, stream>>>(feat, n1, W1, A);
    k_spmm_wave<<<spmmBlocks, 256, 0, stream>>>(ptr, es, A, B);

    // Layer 2
    k_qd_gemm16<<<nodeBlocks, 256, 0, stream>>>(B, n2, W2, A);
    k_spmm_wave<<<spmmBlocks, 256, 0, stream>>>(ptr, es, A, B);

    // Layer 3
    k_qd16<<<nodeBlocks, 256, 0, stream>>>(B, n3, A);
    k_spmm_wave<<<spmmBlocks, 256, 0, stream>>>(ptr, es, A, B);
    k_gemm_out<<<nodeBlocks, 256, 0, stream>>>(B, W3, out);
}